// Round 10
// baseline (75.814 us; speedup 1.0000x reference)
//
#include <hip/hip_runtime.h>
#include <hip/hip_bf16.h>

// GroupedSpatialAttention: B=2, C=256, H=W=64 (N=4096), heads=8, hc=32.
// R10: k_attn software-pipelines the QK->softmax dependency: iter i issues
// QK MFMAs for tile i+1 (K prefetched a stage earlier) and runs softmax+PV
// for tile i whose sa was produced last iteration -> exp never waits on MFMA
// latency. R7 4-wave/256-thr structure (R9's 8-wave: no gain, VGPR 68>64).

typedef short s8v __attribute__((ext_vector_type(8)));      // 8 bf16 (4 VGPR)
typedef float f32x16 __attribute__((ext_vector_type(16)));
typedef float f32x2 __attribute__((ext_vector_type(2)));
typedef unsigned int u32;
typedef unsigned int u32x4 __attribute__((ext_vector_type(4)));

__device__ __forceinline__ u32 cvt_pk_bf16(float lo, float hi){
  u32 d;
  asm("v_cvt_pk_bf16_f32 %0, %1, %2" : "=v"(d) : "v"(lo), "v"(hi));
  return d;
}

// fragment offset (halves) within a 32-row x 256-col panel (A and B identical):
// lane (hi*32+row) reads 8 halves at kk*512 + lane*8 for K-step kk.
__device__ __forceinline__ int frag_off(int row, int c){
  return ((c>>4)<<9) + (((c>>3)&1)<<8) + (row<<3) + (c&7);
}

// ---------- x -> xt fragment-major panels; weights cast fused in ----------
__global__ __launch_bounds__(256) void k_prep(const float* __restrict__ x,
                                              const float* __restrict__ wqkv,
                                              const float* __restrict__ wproj,
                                              __hip_bfloat16* __restrict__ xt,
                                              __hip_bfloat16* __restrict__ wq,
                                              __hip_bfloat16* __restrict__ wp){
  __shared__ float tile[64][65];                 // [c_local][p_local]
  const int b = blockIdx.z;
  const int c0 = blockIdx.y * 64, p0 = blockIdx.x * 64;
  const int tx = threadIdx.x & 63, ty = threadIdx.x >> 6;
  const float* src = x + ((size_t)b*256 + c0)*4096 + p0;
#pragma unroll
  for(int i=0;i<16;i++){
    int r = i*4 + ty;
    tile[r][tx] = src[(size_t)r*4096 + tx];
  }
  // fused weight cast (512 blocks x 64 chunks = 32768 chunks of 8)
  if(threadIdx.x < 64){
    int flat = (blockIdx.z*4 + blockIdx.y)*64 + blockIdx.x;
    int e = flat*64 + threadIdx.x;
    const float* srcw; __hip_bfloat16* dstw;
    if(e < 24576){ srcw = wqkv; dstw = wq; }
    else { e -= 24576; srcw = wproj; dstw = wp; }
    int o = e >> 5, cw = (e & 31)*8;
    const float* s = srcw + (size_t)o*256 + cw;
    u32x4 wv;
    wv.x = cvt_pk_bf16(s[0], s[1]);
    wv.y = cvt_pk_bf16(s[2], s[3]);
    wv.z = cvt_pk_bf16(s[4], s[5]);
    wv.w = cvt_pk_bf16(s[6], s[7]);
    *(u32x4*)(dstw + (size_t)(o>>5)*8192 + frag_off(o & 31, cw)) = wv;
  }
  __syncthreads();
  __hip_bfloat16* dstb = xt + (size_t)b*1048576;
#pragma unroll
  for(int it=0; it<2; ++it){
    int id = it*256 + threadIdx.x;               // 0..511 chunks of 8 c-values
    int pl = id & 63, cc = id >> 6;              // cc 0..7
    int c = c0 + cc*8;
    u32x4 wv;
    wv.x = cvt_pk_bf16(tile[cc*8+0][pl], tile[cc*8+1][pl]);
    wv.y = cvt_pk_bf16(tile[cc*8+2][pl], tile[cc*8+3][pl]);
    wv.z = cvt_pk_bf16(tile[cc*8+4][pl], tile[cc*8+5][pl]);
    wv.w = cvt_pk_bf16(tile[cc*8+6][pl], tile[cc*8+7][pl]);
    int panel = (p0 + pl) >> 5;
    *(u32x4*)(dstb + (size_t)panel*8192 + frag_off(pl & 31, c)) = wv;
  }
}

// ---------- QKV GEMM, 2x2 wave-tiles + 1-deep prefetch ----------
__global__ __launch_bounds__(256) void k_qkv(const __hip_bfloat16* __restrict__ w,
                                             const __hip_bfloat16* __restrict__ xt,
                                             __hip_bfloat16* __restrict__ qb,
                                             __hip_bfloat16* __restrict__ kb,
                                             __hip_bfloat16* __restrict__ vt){
  const int wave = threadIdx.x >> 6, lane = threadIdx.x & 63;
  const int l31 = lane & 31, hi = lane >> 5;
  const int t = blockIdx.x*4 + wave;             // 0..1535
  const int ntp = t & 127, mtp = t >> 7;         // 128 nt-pairs x 12 mt-pairs
  const __hip_bfloat16* a0 = w  + (size_t)(2*mtp)*8192 + lane*8;
  const __hip_bfloat16* b0 = xt + (size_t)(2*ntp)*8192 + lane*8;
  f32x16 acc00, acc01, acc10, acc11;
#pragma unroll
  for(int i=0;i<16;i++){ acc00[i]=0.f; acc01[i]=0.f; acc10[i]=0.f; acc11[i]=0.f; }
  s8v af0 = *(const s8v*)a0,            af1 = *(const s8v*)(a0 + 8192);
  s8v bf0 = *(const s8v*)b0,            bf1 = *(const s8v*)(b0 + 8192);
  for(int kk=0;kk<15;kk++){
    const __hip_bfloat16* an = a0 + (kk+1)*512;
    const __hip_bfloat16* bn = b0 + (kk+1)*512;
    s8v na0 = *(const s8v*)an, na1 = *(const s8v*)(an + 8192);
    s8v nb0 = *(const s8v*)bn, nb1 = *(const s8v*)(bn + 8192);
    acc00 = __builtin_amdgcn_mfma_f32_32x32x16_bf16(af0, bf0, acc00, 0,0,0);
    acc01 = __builtin_amdgcn_mfma_f32_32x32x16_bf16(af0, bf1, acc01, 0,0,0);
    acc10 = __builtin_amdgcn_mfma_f32_32x32x16_bf16(af1, bf0, acc10, 0,0,0);
    acc11 = __builtin_amdgcn_mfma_f32_32x32x16_bf16(af1, bf1, acc11, 0,0,0);
    af0 = na0; af1 = na1; bf0 = nb0; bf1 = nb1;
  }
  acc00 = __builtin_amdgcn_mfma_f32_32x32x16_bf16(af0, bf0, acc00, 0,0,0);
  acc01 = __builtin_amdgcn_mfma_f32_32x32x16_bf16(af0, bf1, acc01, 0,0,0);
  acc10 = __builtin_amdgcn_mfma_f32_32x32x16_bf16(af1, bf0, acc10, 0,0,0);
  acc11 = __builtin_amdgcn_mfma_f32_32x32x16_bf16(af1, bf1, acc11, 0,0,0);

  const int region = mtp >> 2;                   // 0=q 1=k 2=v (uniform per wave)
  const float s = (region==0) ? (0.17677669529663687f * 1.4426950408889634f) : 1.0f;
#pragma unroll
  for(int mi=0; mi<2; ++mi){
#pragma unroll
    for(int ni=0; ni<2; ++ni){
      const f32x16& acc = (mi==0) ? (ni==0?acc00:acc01) : (ni==0?acc10:acc11);
      const int mt = 2*mtp + mi, nt = 2*ntp + ni;
      const int bb = nt >> 7, ktile = nt & 127, h = mt & 7;
      const size_t tbase = (size_t)(bb*8 + h)*131072 + (size_t)ktile*1024;
      if(region < 2){
        __hip_bfloat16* dst = (region==0 ? qb : kb) + tbase + l31*8 + 4*hi;
#pragma unroll
        for(int g=0; g<4; ++g){
          uint2 wv;
          wv.x = cvt_pk_bf16(acc[4*g+0]*s, acc[4*g+1]*s);
          wv.y = cvt_pk_bf16(acc[4*g+2]*s, acc[4*g+3]*s);
          *(uint2*)(dst + (g>>1)*512 + (g&1)*256) = wv;   // c = 8g+4hi+{0..3}
        }
      } else {
        // tau layout: key=l31 -> j=key>>4, hv=(key>>2)&1, t=((key>>3)&1)*4+(key&3)
        const int j = l31 >> 4, hv = (l31 >> 2) & 1, tt = ((l31>>3)&1)*4 + (l31&3);
        __hip_bfloat16* dst = vt + tbase + j*512 + hv*256 + tt;
#pragma unroll
        for(int r=0;r<16;++r){
          int c = (r&3) + 8*(r>>2) + 4*hi;
          dst[c*8] = __float2bfloat16(acc[r]);
        }
      }
    }
  }
}

// ---------- flash attention: 256-thr block = 64 queries, 4 waves x 32 KV tiles,
// XCD-swizzled grid; sa-PIPELINED: iter i issues QK(i+1), consumes tile i ----------
__global__ __launch_bounds__(256) void k_attn(const __hip_bfloat16* __restrict__ qb,
                                              const __hip_bfloat16* __restrict__ kb,
                                              const __hip_bfloat16* __restrict__ vt,
                                              __hip_bfloat16* __restrict__ ost){
  __shared__ float part[4][64][33];              // [wave][q][c] padded
  __shared__ float lsl[4][64];
  const int wave = threadIdx.x >> 6, lane = threadIdx.x & 63;
  const int l31 = lane & 31, hi = lane >> 5;
  const int vid = (blockIdx.x & 7)*128 + (blockIdx.x >> 3);  // XCD swizzle (bijective)
  const int bh = vid >> 6, qc = vid & 63;        // 64-query chunk

  const __hip_bfloat16* qt = qb + (size_t)bh*131072 + (size_t)(qc*2)*1024 + (size_t)lane*8;
  const s8v qfA0 = *(const s8v*)qt;
  const s8v qfA1 = *(const s8v*)(qt + 512);
  const s8v qfB0 = *(const s8v*)(qt + 1024);
  const s8v qfB1 = *(const s8v*)(qt + 1536);

  const __hip_bfloat16* kp = kb + (size_t)bh*131072 + (size_t)(wave*32)*1024 + (size_t)lane*8;
  const __hip_bfloat16* vp = vt + (size_t)bh*131072 + (size_t)(wave*32)*1024 + (size_t)lane*8;

  f32x16 zf;
#pragma unroll
  for(int i=0;i<16;i++) zf[i]=0.f;
  f32x16 oaccA, oaccB;                           // O^T[c][q], col q=l31
#pragma unroll
  for(int i=0;i<16;i++){ oaccA[i]=0.f; oaccB[i]=0.f; }
  f32x2 sA0={0.f,0.f}, sA1={0.f,0.f}, sB0={0.f,0.f}, sB1={0.f,0.f};

  // consume tile whose scores are in saA/saB and V-frags vf0/vf1
  auto consume = [&](const f32x16& saA, const f32x16& saB, s8v vf0, s8v vf1){
    float pvA[16], pvB[16];
#pragma unroll
    for(int r=0;r<16;++r) pvA[r] = __builtin_amdgcn_exp2f(saA[r]);
#pragma unroll
    for(int r=0;r<16;++r) pvB[r] = __builtin_amdgcn_exp2f(saB[r]);
    sA0 += (f32x2){pvA[0],pvA[1]};   sA1 += (f32x2){pvA[2],pvA[3]};
    sA0 += (f32x2){pvA[4],pvA[5]};   sA1 += (f32x2){pvA[6],pvA[7]};
    sA0 += (f32x2){pvA[8],pvA[9]};   sA1 += (f32x2){pvA[10],pvA[11]};
    sA0 += (f32x2){pvA[12],pvA[13]}; sA1 += (f32x2){pvA[14],pvA[15]};
    sB0 += (f32x2){pvB[0],pvB[1]};   sB1 += (f32x2){pvB[2],pvB[3]};
    sB0 += (f32x2){pvB[4],pvB[5]};   sB1 += (f32x2){pvB[6],pvB[7]};
    sB0 += (f32x2){pvB[8],pvB[9]};   sB1 += (f32x2){pvB[10],pvB[11]};
    sB0 += (f32x2){pvB[12],pvB[13]}; sB1 += (f32x2){pvB[14],pvB[15]};

    u32x4 wA0, wA1, wB0, wB1;
    wA0.x = cvt_pk_bf16(pvA[0],  pvA[1]);   wA0.y = cvt_pk_bf16(pvA[2],  pvA[3]);
    wA0.z = cvt_pk_bf16(pvA[4],  pvA[5]);   wA0.w = cvt_pk_bf16(pvA[6],  pvA[7]);
    wA1.x = cvt_pk_bf16(pvA[8],  pvA[9]);   wA1.y = cvt_pk_bf16(pvA[10], pvA[11]);
    wA1.z = cvt_pk_bf16(pvA[12], pvA[13]);  wA1.w = cvt_pk_bf16(pvA[14], pvA[15]);
    wB0.x = cvt_pk_bf16(pvB[0],  pvB[1]);   wB0.y = cvt_pk_bf16(pvB[2],  pvB[3]);
    wB0.z = cvt_pk_bf16(pvB[4],  pvB[5]);   wB0.w = cvt_pk_bf16(pvB[6],  pvB[7]);
    wB1.x = cvt_pk_bf16(pvB[8],  pvB[9]);   wB1.y = cvt_pk_bf16(pvB[10], pvB[11]);
    wB1.z = cvt_pk_bf16(pvB[12], pvB[13]);  wB1.w = cvt_pk_bf16(pvB[14], pvB[15]);

    __builtin_amdgcn_s_setprio(1);
    oaccA = __builtin_amdgcn_mfma_f32_32x32x16_bf16(vf0, __builtin_bit_cast(s8v, wA0), oaccA, 0,0,0);
    oaccA = __builtin_amdgcn_mfma_f32_32x32x16_bf16(vf1, __builtin_bit_cast(s8v, wA1), oaccA, 0,0,0);
    oaccB = __builtin_amdgcn_mfma_f32_32x32x16_bf16(vf0, __builtin_bit_cast(s8v, wB0), oaccB, 0,0,0);
    oaccB = __builtin_amdgcn_mfma_f32_32x32x16_bf16(vf1, __builtin_bit_cast(s8v, wB1), oaccB, 0,0,0);
    __builtin_amdgcn_s_setprio(0);
  };

  // prologue: sa for tile 0; K(1) staged; V(0) staged
  s8v kf0 = *(const s8v*)kp, kf1 = *(const s8v*)(kp + 512);
  s8v vf0 = *(const s8v*)vp, vf1 = *(const s8v*)(vp + 512);
  f32x16 saA = __builtin_amdgcn_mfma_f32_32x32x16_bf16(kf0, qfA0, zf, 0,0,0);
  saA = __builtin_amdgcn_mfma_f32_32x32x16_bf16(kf1, qfA1, saA, 0,0,0);
  f32x16 saB = __builtin_amdgcn_mfma_f32_32x32x16_bf16(kf0, qfB0, zf, 0,0,0);
  saB = __builtin_amdgcn_mfma_f32_32x32x16_bf16(kf1, qfB1, saB, 0,0,0);
  kf0 = *(const s8v*)(kp + 1024); kf1 = *(const s8v*)(kp + 1536);   // K(1)

  for(int i=0;i<31;++i){
    const int ip2 = (i+2 <= 31) ? i+2 : 31;
    const __hip_bfloat16* nkp = kp + (size_t)ip2*1024;
    const __hip_bfloat16* nvp = vp + (size_t)(i+1)*1024;
    s8v nk0 = *(const s8v*)nkp, nk1 = *(const s8v*)(nkp + 512);
    s8v nv0 = *(const s8v*)nvp, nv1 = *(const s8v*)(nvp + 512);
    // issue QK for tile i+1 (K staged last iter); result consumed next iter
    __builtin_amdgcn_s_setprio(1);
    f32x16 saAn = __builtin_amdgcn_mfma_f32_32x32x16_bf16(kf0, qfA0, zf, 0,0,0);
    saAn = __builtin_amdgcn_mfma_f32_32x32x16_bf16(kf1, qfA1, saAn, 0,0,0);
    f32x16 saBn = __builtin_amdgcn_mfma_f32_32x32x16_bf16(kf0, qfB0, zf, 0,0,0);
    saBn = __builtin_amdgcn_mfma_f32_32x32x16_bf16(kf1, qfB1, saBn, 0,0,0);
    __builtin_amdgcn_s_setprio(0);
    // softmax+PV for tile i (sa produced last iter -> no MFMA-latency stall)
    consume(saA, saB, vf0, vf1);
    saA = saAn; saB = saBn;
    kf0 = nk0; kf1 = nk1; vf0 = nv0; vf1 = nv1;
  }
  consume(saA, saB, vf0, vf1);                   // tile 31

  float lsumA = (sA0.x + sA0.y) + (sA1.x + sA1.y);
  float lsumB = (sB0.x + sB0.y) + (sB1.x + sB1.y);
  lsumA += __shfl_xor(lsumA, 32, 64);            // other 16-key half
  lsumB += __shfl_xor(lsumB, 32, 64);
  lsl[wave][l31] = lsumA;
  lsl[wave][32 + l31] = lsumB;
#pragma unroll
  for(int r=0;r<16;++r){
    int c = (r&3) + 8*(r>>2) + 4*hi;
    part[wave][l31][c] = oaccA[r];
    part[wave][32 + l31][c] = oaccB[r];
  }
  __syncthreads();

  // reduce 4 partials, write ost in proj-B fragment-major order
  const int b = bh >> 3, h = bh & 7;
  __hip_bfloat16* obase = ost + (size_t)(b*128 + qc*2)*8192;
#pragma unroll
  for(int it=0; it<8; ++it){
    int e = it*256 + threadIdx.x;
    int q = e >> 5, c = e & 31;                  // q 0..63, c 0..31
    float o = (part[0][q][c] + part[1][q][c]) + (part[2][q][c] + part[3][q][c]);
    float L = (lsl[0][q] + lsl[1][q]) + (lsl[2][q] + lsl[3][q]);
    obase[(size_t)(q>>5)*8192 + (h*2 + (c>>4))*512 + ((c>>3)&1)*256 + (q&31)*8 + (c&7)]
        = __float2bfloat16(o / L);
  }
}

// ---------- proj GEMM: out[b][o][p] = sum_c2 Wp[o][c2] * Ost[b][p][c2] ----------
__global__ __launch_bounds__(256) void k_proj(const __hip_bfloat16* __restrict__ w,
                                              const __hip_bfloat16* __restrict__ ost,
                                              float* __restrict__ out){
  const int wave = threadIdx.x >> 6, lane = threadIdx.x & 63;
  const int l31 = lane & 31, hi = lane >> 5;
  const int t = blockIdx.x*4 + wave;             // 8 mt x 256 nt wave-tiles
  const int nt = t & 255, mt = t >> 8;
  const __hip_bfloat16* arow = w   + (size_t)mt*8192 + lane*8;
  const __hip_bfloat16* brow = ost + (size_t)nt*8192 + lane*8;
  f32x16 acc;
#pragma unroll
  for(int i=0;i<16;i++) acc[i]=0.f;
  s8v a = *(const s8v*)arow, b = *(const s8v*)brow;
  for(int kk=0;kk<15;kk++){
    s8v na = *(const s8v*)(arow + (kk+1)*512);
    s8v nb = *(const s8v*)(brow + (kk+1)*512);
    acc = __builtin_amdgcn_mfma_f32_32x32x16_bf16(a, b, acc, 0,0,0);
    a = na; b = nb;
  }
  acc = __builtin_amdgcn_mfma_f32_32x32x16_bf16(a, b, acc, 0,0,0);
  const int pg = nt*32 + l31;
  const int bb = pg >> 12, p = pg & 4095;
  float* dst = out + (size_t)bb*1048576 + p;
#pragma unroll
  for(int r=0;r<16;++r){
    int o = mt*32 + (r&3) + 8*(r>>2) + 4*hi;
    dst[(size_t)o*4096] = acc[r];                // coalesced across lanes (p)
  }
}

extern "C" void kernel_launch(void* const* d_in, const int* in_sizes, int n_in,
                              void* d_out, int out_size, void* d_ws, size_t ws_size,
                              hipStream_t stream){
  const float* x     = (const float*)d_in[0];
  const float* wqkv  = (const float*)d_in[1];
  const float* wproj = (const float*)d_in[2];
  float* out = (float*)d_out;

  const size_t SZ_XT = (size_t)8192*256*2;   // 4 MB (reused as Ost)
  const size_t SZ_VT = (size_t)16*32*4096*2; // 4 MB
  const size_t SZ_WQ = (size_t)768*256*2;
  const size_t SZ_WP = (size_t)256*256*2;
  if(ws_size < SZ_XT + SZ_VT + SZ_WQ + SZ_WP) return;   // need ~8.9 MB scratch

  char* ws = (char*)d_ws;
  __hip_bfloat16* xt  = (__hip_bfloat16*)ws;
  __hip_bfloat16* vt  = (__hip_bfloat16*)(ws + SZ_XT);
  __hip_bfloat16* wqb = (__hip_bfloat16*)(ws + SZ_XT + SZ_VT);
  __hip_bfloat16* wpb = (__hip_bfloat16*)(ws + SZ_XT + SZ_VT + SZ_WQ);
  // q,k live in d_out (8 MB): dead before proj overwrites d_out with the result.
  __hip_bfloat16* qb  = (__hip_bfloat16*)d_out;
  __hip_bfloat16* kb  = qb + (size_t)2*1024*1024;
  __hip_bfloat16* ost = xt;                   // xt dead after k_qkv

  k_prep<<<dim3(64,4,2), 256, 0, stream>>>(x, wqkv, wproj, xt, wqb, wpb);
  k_qkv<<<384, 256, 0, stream>>>(wqb, xt, qb, kb, vt);
  k_attn<<<1024, 256, 0, stream>>>(qb, kb, vt, ost);
  k_proj<<<512, 256, 0, stream>>>(wpb, ost, out);
}

// Round 11
// 73.412 us; speedup vs baseline: 1.0327x; 1.0327x over previous
//
#include <hip/hip_runtime.h>
#include <hip/hip_bf16.h>

// GroupedSpatialAttention: B=2, C=256, H=W=64 (N=4096), heads=8, hc=32.
// R11: R7 structure (best: 49.6us) + MFMA-fused Schraudolph exp2:
//  - q stored with scale hc^-0.5 * log2e * 2^23 folded in (bf16 scale-free)
//  - QK accumulator initialized to (127-sigma)*2^23 (the Schraudolph bias)
//  - exp2(x) == bitcast(int(sa)) -> one full-rate v_cvt_i32_f32 per score,
//    TRANS pipe (16cy/exp2, ~27us of issue floor) eliminated entirely.

typedef short s8v __attribute__((ext_vector_type(8)));      // 8 bf16 (4 VGPR)
typedef float f32x16 __attribute__((ext_vector_type(16)));
typedef float f32x2 __attribute__((ext_vector_type(2)));
typedef unsigned int u32;
typedef unsigned int u32x4 __attribute__((ext_vector_type(4)));

__device__ __forceinline__ u32 cvt_pk_bf16(float lo, float hi){
  u32 d;
  asm("v_cvt_pk_bf16_f32 %0, %1, %2" : "=v"(d) : "v"(lo), "v"(hi));
  return d;
}

// Schraudolph bias as float: (127 - 0.0347) * 2^23 (minimax-centered)
#define SCH_BIAS_F ((float)((127.0 - 0.0347) * 8388608.0))
// q scale: hc^-0.5 * log2e * 2^23
#define Q_SCALE_F ((float)(0.17677669529663687 * 1.4426950408889634 * 8388608.0))

// fragment offset (halves) within a 32-row x 256-col panel (A and B identical):
// lane (hi*32+row) reads 8 halves at kk*512 + lane*8 for K-step kk.
__device__ __forceinline__ int frag_off(int row, int c){
  return ((c>>4)<<9) + (((c>>3)&1)<<8) + (row<<3) + (c&7);
}

// ---------- x -> xt fragment-major panels; weights cast fused in ----------
__global__ __launch_bounds__(256) void k_prep(const float* __restrict__ x,
                                              const float* __restrict__ wqkv,
                                              const float* __restrict__ wproj,
                                              __hip_bfloat16* __restrict__ xt,
                                              __hip_bfloat16* __restrict__ wq,
                                              __hip_bfloat16* __restrict__ wp){
  __shared__ float tile[64][65];                 // [c_local][p_local]
  const int b = blockIdx.z;
  const int c0 = blockIdx.y * 64, p0 = blockIdx.x * 64;
  const int tx = threadIdx.x & 63, ty = threadIdx.x >> 6;
  const float* src = x + ((size_t)b*256 + c0)*4096 + p0;
#pragma unroll
  for(int i=0;i<16;i++){
    int r = i*4 + ty;
    tile[r][tx] = src[(size_t)r*4096 + tx];
  }
  // fused weight cast (512 blocks x 64 chunks = 32768 chunks of 8)
  if(threadIdx.x < 64){
    int flat = (blockIdx.z*4 + blockIdx.y)*64 + blockIdx.x;
    int e = flat*64 + threadIdx.x;
    const float* srcw; __hip_bfloat16* dstw;
    if(e < 24576){ srcw = wqkv; dstw = wq; }
    else { e -= 24576; srcw = wproj; dstw = wp; }
    int o = e >> 5, cw = (e & 31)*8;
    const float* s = srcw + (size_t)o*256 + cw;
    u32x4 wv;
    wv.x = cvt_pk_bf16(s[0], s[1]);
    wv.y = cvt_pk_bf16(s[2], s[3]);
    wv.z = cvt_pk_bf16(s[4], s[5]);
    wv.w = cvt_pk_bf16(s[6], s[7]);
    *(u32x4*)(dstw + (size_t)(o>>5)*8192 + frag_off(o & 31, cw)) = wv;
  }
  __syncthreads();
  __hip_bfloat16* dstb = xt + (size_t)b*1048576;
#pragma unroll
  for(int it=0; it<2; ++it){
    int id = it*256 + threadIdx.x;               // 0..511 chunks of 8 c-values
    int pl = id & 63, cc = id >> 6;              // cc 0..7
    int c = c0 + cc*8;
    u32x4 wv;
    wv.x = cvt_pk_bf16(tile[cc*8+0][pl], tile[cc*8+1][pl]);
    wv.y = cvt_pk_bf16(tile[cc*8+2][pl], tile[cc*8+3][pl]);
    wv.z = cvt_pk_bf16(tile[cc*8+4][pl], tile[cc*8+5][pl]);
    wv.w = cvt_pk_bf16(tile[cc*8+6][pl], tile[cc*8+7][pl]);
    int panel = (p0 + pl) >> 5;
    *(u32x4*)(dstb + (size_t)panel*8192 + frag_off(pl & 31, c)) = wv;
  }
}

// ---------- QKV GEMM, 2x2 wave-tiles + 1-deep prefetch ----------
__global__ __launch_bounds__(256) void k_qkv(const __hip_bfloat16* __restrict__ w,
                                             const __hip_bfloat16* __restrict__ xt,
                                             __hip_bfloat16* __restrict__ qb,
                                             __hip_bfloat16* __restrict__ kb,
                                             __hip_bfloat16* __restrict__ vt){
  const int wave = threadIdx.x >> 6, lane = threadIdx.x & 63;
  const int l31 = lane & 31, hi = lane >> 5;
  const int t = blockIdx.x*4 + wave;             // 0..1535
  const int ntp = t & 127, mtp = t >> 7;         // 128 nt-pairs x 12 mt-pairs
  const __hip_bfloat16* a0 = w  + (size_t)(2*mtp)*8192 + lane*8;
  const __hip_bfloat16* b0 = xt + (size_t)(2*ntp)*8192 + lane*8;
  f32x16 acc00, acc01, acc10, acc11;
#pragma unroll
  for(int i=0;i<16;i++){ acc00[i]=0.f; acc01[i]=0.f; acc10[i]=0.f; acc11[i]=0.f; }
  s8v af0 = *(const s8v*)a0,            af1 = *(const s8v*)(a0 + 8192);
  s8v bf0 = *(const s8v*)b0,            bf1 = *(const s8v*)(b0 + 8192);
  for(int kk=0;kk<15;kk++){
    const __hip_bfloat16* an = a0 + (kk+1)*512;
    const __hip_bfloat16* bn = b0 + (kk+1)*512;
    s8v na0 = *(const s8v*)an, na1 = *(const s8v*)(an + 8192);
    s8v nb0 = *(const s8v*)bn, nb1 = *(const s8v*)(bn + 8192);
    acc00 = __builtin_amdgcn_mfma_f32_32x32x16_bf16(af0, bf0, acc00, 0,0,0);
    acc01 = __builtin_amdgcn_mfma_f32_32x32x16_bf16(af0, bf1, acc01, 0,0,0);
    acc10 = __builtin_amdgcn_mfma_f32_32x32x16_bf16(af1, bf0, acc10, 0,0,0);
    acc11 = __builtin_amdgcn_mfma_f32_32x32x16_bf16(af1, bf1, acc11, 0,0,0);
    af0 = na0; af1 = na1; bf0 = nb0; bf1 = nb1;
  }
  acc00 = __builtin_amdgcn_mfma_f32_32x32x16_bf16(af0, bf0, acc00, 0,0,0);
  acc01 = __builtin_amdgcn_mfma_f32_32x32x16_bf16(af0, bf1, acc01, 0,0,0);
  acc10 = __builtin_amdgcn_mfma_f32_32x32x16_bf16(af1, bf0, acc10, 0,0,0);
  acc11 = __builtin_amdgcn_mfma_f32_32x32x16_bf16(af1, bf1, acc11, 0,0,0);

  const int region = mtp >> 2;                   // 0=q 1=k 2=v (uniform per wave)
  const float s = (region==0) ? Q_SCALE_F : 1.0f;
#pragma unroll
  for(int mi=0; mi<2; ++mi){
#pragma unroll
    for(int ni=0; ni<2; ++ni){
      const f32x16& acc = (mi==0) ? (ni==0?acc00:acc01) : (ni==0?acc10:acc11);
      const int mt = 2*mtp + mi, nt = 2*ntp + ni;
      const int bb = nt >> 7, ktile = nt & 127, h = mt & 7;
      const size_t tbase = (size_t)(bb*8 + h)*131072 + (size_t)ktile*1024;
      if(region < 2){
        __hip_bfloat16* dst = (region==0 ? qb : kb) + tbase + l31*8 + 4*hi;
#pragma unroll
        for(int g=0; g<4; ++g){
          uint2 wv;
          wv.x = cvt_pk_bf16(acc[4*g+0]*s, acc[4*g+1]*s);
          wv.y = cvt_pk_bf16(acc[4*g+2]*s, acc[4*g+3]*s);
          *(uint2*)(dst + (g>>1)*512 + (g&1)*256) = wv;   // c = 8g+4hi+{0..3}
        }
      } else {
        // tau layout: key=l31 -> j=key>>4, hv=(key>>2)&1, t=((key>>3)&1)*4+(key&3)
        const int j = l31 >> 4, hv = (l31 >> 2) & 1, tt = ((l31>>3)&1)*4 + (l31&3);
        __hip_bfloat16* dst = vt + tbase + j*512 + hv*256 + tt;
#pragma unroll
        for(int r=0;r<16;++r){
          int c = (r&3) + 8*(r>>2) + 4*hi;
          dst[c*8] = __float2bfloat16(acc[r]);
        }
      }
    }
  }
}

// ---------- flash attention: 256-thr block = 64 queries, 4 waves x 32 KV tiles,
// XCD-swizzled grid, 1-deep register prefetch, setprio; Schraudolph exp via
// cvt_i32 (scale folded into q, bias folded into the QK accumulator init) ----------
__global__ __launch_bounds__(256) void k_attn(const __hip_bfloat16* __restrict__ qb,
                                              const __hip_bfloat16* __restrict__ kb,
                                              const __hip_bfloat16* __restrict__ vt,
                                              __hip_bfloat16* __restrict__ ost){
  __shared__ float part[4][64][33];              // [wave][q][c] padded
  __shared__ float lsl[4][64];
  const int wave = threadIdx.x >> 6, lane = threadIdx.x & 63;
  const int l31 = lane & 31, hi = lane >> 5;
  const int vid = (blockIdx.x & 7)*128 + (blockIdx.x >> 3);  // XCD swizzle (bijective)
  const int bh = vid >> 6, qc = vid & 63;        // 64-query chunk

  const __hip_bfloat16* qt = qb + (size_t)bh*131072 + (size_t)(qc*2)*1024 + (size_t)lane*8;
  const s8v qfA0 = *(const s8v*)qt;
  const s8v qfA1 = *(const s8v*)(qt + 512);
  const s8v qfB0 = *(const s8v*)(qt + 1024);
  const s8v qfB1 = *(const s8v*)(qt + 1536);

  const __hip_bfloat16* kp = kb + (size_t)bh*131072 + (size_t)(wave*32)*1024 + (size_t)lane*8;
  const __hip_bfloat16* vp = vt + (size_t)bh*131072 + (size_t)(wave*32)*1024 + (size_t)lane*8;

  f32x16 zf;                                     // Schraudolph bias as C-init
#pragma unroll
  for(int i=0;i<16;i++) zf[i] = SCH_BIAS_F;
  f32x16 oaccA, oaccB;                           // O^T[c][q], col q=l31
#pragma unroll
  for(int i=0;i<16;i++){ oaccA[i]=0.f; oaccB[i]=0.f; }
  f32x2 sA0={0.f,0.f}, sA1={0.f,0.f}, sB0={0.f,0.f}, sB1={0.f,0.f};

  auto compute = [&](s8v kf0, s8v kf1, s8v vf0, s8v vf1){
    __builtin_amdgcn_s_setprio(1);
    f32x16 saA = __builtin_amdgcn_mfma_f32_32x32x16_bf16(kf0, qfA0, zf, 0,0,0);
    saA = __builtin_amdgcn_mfma_f32_32x32x16_bf16(kf1, qfA1, saA, 0,0,0);
    f32x16 saB = __builtin_amdgcn_mfma_f32_32x32x16_bf16(kf0, qfB0, zf, 0,0,0);
    saB = __builtin_amdgcn_mfma_f32_32x32x16_bf16(kf1, qfB1, saB, 0,0,0);
    __builtin_amdgcn_s_setprio(0);
    // sa[r] = 2^23*(x+127-sigma), x = logit*scale*log2e; key=(r&3)+8*(r>>2)+4hi
    // exp2(x) ~= bitcast(int(sa)) -- one full-rate cvt per score, no TRANS.
    float pvA[16], pvB[16];
#pragma unroll
    for(int r=0;r<16;++r) pvA[r] = __builtin_bit_cast(float, (int)saA[r]);
#pragma unroll
    for(int r=0;r<16;++r) pvB[r] = __builtin_bit_cast(float, (int)saB[r]);
    sA0 += (f32x2){pvA[0],pvA[1]};   sA1 += (f32x2){pvA[2],pvA[3]};
    sA0 += (f32x2){pvA[4],pvA[5]};   sA1 += (f32x2){pvA[6],pvA[7]};
    sA0 += (f32x2){pvA[8],pvA[9]};   sA1 += (f32x2){pvA[10],pvA[11]};
    sA0 += (f32x2){pvA[12],pvA[13]}; sA1 += (f32x2){pvA[14],pvA[15]};
    sB0 += (f32x2){pvB[0],pvB[1]};   sB1 += (f32x2){pvB[2],pvB[3]};
    sB0 += (f32x2){pvB[4],pvB[5]};   sB1 += (f32x2){pvB[6],pvB[7]};
    sB0 += (f32x2){pvB[8],pvB[9]};   sB1 += (f32x2){pvB[10],pvB[11]};
    sB0 += (f32x2){pvB[12],pvB[13]}; sB1 += (f32x2){pvB[14],pvB[15]};

    u32x4 wA0, wA1, wB0, wB1;
    wA0.x = cvt_pk_bf16(pvA[0],  pvA[1]);   wA0.y = cvt_pk_bf16(pvA[2],  pvA[3]);
    wA0.z = cvt_pk_bf16(pvA[4],  pvA[5]);   wA0.w = cvt_pk_bf16(pvA[6],  pvA[7]);
    wA1.x = cvt_pk_bf16(pvA[8],  pvA[9]);   wA1.y = cvt_pk_bf16(pvA[10], pvA[11]);
    wA1.z = cvt_pk_bf16(pvA[12], pvA[13]);  wA1.w = cvt_pk_bf16(pvA[14], pvA[15]);
    wB0.x = cvt_pk_bf16(pvB[0],  pvB[1]);   wB0.y = cvt_pk_bf16(pvB[2],  pvB[3]);
    wB0.z = cvt_pk_bf16(pvB[4],  pvB[5]);   wB0.w = cvt_pk_bf16(pvB[6],  pvB[7]);
    wB1.x = cvt_pk_bf16(pvB[8],  pvB[9]);   wB1.y = cvt_pk_bf16(pvB[10], pvB[11]);
    wB1.z = cvt_pk_bf16(pvB[12], pvB[13]);  wB1.w = cvt_pk_bf16(pvB[14], pvB[15]);

    __builtin_amdgcn_s_setprio(1);
    oaccA = __builtin_amdgcn_mfma_f32_32x32x16_bf16(vf0, __builtin_bit_cast(s8v, wA0), oaccA, 0,0,0);
    oaccA = __builtin_amdgcn_mfma_f32_32x32x16_bf16(vf1, __builtin_bit_cast(s8v, wA1), oaccA, 0,0,0);
    oaccB = __builtin_amdgcn_mfma_f32_32x32x16_bf16(vf0, __builtin_bit_cast(s8v, wB0), oaccB, 0,0,0);
    oaccB = __builtin_amdgcn_mfma_f32_32x32x16_bf16(vf1, __builtin_bit_cast(s8v, wB1), oaccB, 0,0,0);
    __builtin_amdgcn_s_setprio(0);
  };

  // software pipeline: prefetch iter i+1's K/V during iter i's compute
  s8v kf0 = *(const s8v*)kp, kf1 = *(const s8v*)(kp + 512);
  s8v vf0 = *(const s8v*)vp, vf1 = *(const s8v*)(vp + 512);
  for(int i=0;i<31;++i){
    const __hip_bfloat16* nkp = kp + (size_t)(i+1)*1024;
    const __hip_bfloat16* nvp = vp + (size_t)(i+1)*1024;
    s8v nk0 = *(const s8v*)nkp, nk1 = *(const s8v*)(nkp + 512);
    s8v nv0 = *(const s8v*)nvp, nv1 = *(const s8v*)(nvp + 512);
    compute(kf0, kf1, vf0, vf1);
    kf0 = nk0; kf1 = nk1; vf0 = nv0; vf1 = nv1;
  }
  compute(kf0, kf1, vf0, vf1);

  float lsumA = (sA0.x + sA0.y) + (sA1.x + sA1.y);
  float lsumB = (sB0.x + sB0.y) + (sB1.x + sB1.y);
  lsumA += __shfl_xor(lsumA, 32, 64);            // other 16-key half
  lsumB += __shfl_xor(lsumB, 32, 64);
  lsl[wave][l31] = lsumA;
  lsl[wave][32 + l31] = lsumB;
#pragma unroll
  for(int r=0;r<16;++r){
    int c = (r&3) + 8*(r>>2) + 4*hi;
    part[wave][l31][c] = oaccA[r];
    part[wave][32 + l31][c] = oaccB[r];
  }
  __syncthreads();

  // reduce 4 partials, write ost in proj-B fragment-major order
  const int b = bh >> 3, h = bh & 7;
  __hip_bfloat16* obase = ost + (size_t)(b*128 + qc*2)*8192;
#pragma unroll
  for(int it=0; it<8; ++it){
    int e = it*256 + threadIdx.x;
    int q = e >> 5, c = e & 31;                  // q 0..63, c 0..31
    float o = (part[0][q][c] + part[1][q][c]) + (part[2][q][c] + part[3][q][c]);
    float L = (lsl[0][q] + lsl[1][q]) + (lsl[2][q] + lsl[3][q]);
    obase[(size_t)(q>>5)*8192 + (h*2 + (c>>4))*512 + ((c>>3)&1)*256 + (q&31)*8 + (c&7)]
        = __float2bfloat16(o / L);
  }
}

// ---------- proj GEMM: out[b][o][p] = sum_c2 Wp[o][c2] * Ost[b][p][c2] ----------
__global__ __launch_bounds__(256) void k_proj(const __hip_bfloat16* __restrict__ w,
                                              const __hip_bfloat16* __restrict__ ost,
                                              float* __restrict__ out){
  const int wave = threadIdx.x >> 6, lane = threadIdx.x & 63;
  const int l31 = lane & 31, hi = lane >> 5;
  const int t = blockIdx.x*4 + wave;             // 8 mt x 256 nt wave-tiles
  const int nt = t & 255, mt = t >> 8;
  const __hip_bfloat16* arow = w   + (size_t)mt*8192 + lane*8;
  const __hip_bfloat16* brow = ost + (size_t)nt*8192 + lane*8;
  f32x16 acc;
#pragma unroll
  for(int i=0;i<16;i++) acc[i]=0.f;
  s8v a = *(const s8v*)arow, b = *(const s8v*)brow;
  for(int kk=0;kk<15;kk++){
    s8v na = *(const s8v*)(arow + (kk+1)*512);
    s8v nb = *(const s8v*)(brow + (kk+1)*512);
    acc = __builtin_amdgcn_mfma_f32_32x32x16_bf16(a, b, acc, 0,0,0);
    a = na; b = nb;
  }
  acc = __builtin_amdgcn_mfma_f32_32x32x16_bf16(a, b, acc, 0,0,0);
  const int pg = nt*32 + l31;
  const int bb = pg >> 12, p = pg & 4095;
  float* dst = out + (size_t)bb*1048576 + p;
#pragma unroll
  for(int r=0;r<16;++r){
    int o = mt*32 + (r&3) + 8*(r>>2) + 4*hi;
    dst[(size_t)o*4096] = acc[r];                // coalesced across lanes (p)
  }
}

extern "C" void kernel_launch(void* const* d_in, const int* in_sizes, int n_in,
                              void* d_out, int out_size, void* d_ws, size_t ws_size,
                              hipStream_t stream){
  const float* x     = (const float*)d_in[0];
  const float* wqkv  = (const float*)d_in[1];
  const float* wproj = (const float*)d_in[2];
  float* out = (float*)d_out;

  const size_t SZ_XT = (size_t)8192*256*2;   // 4 MB (reused as Ost)
  const size_t SZ_VT = (size_t)16*32*4096*2; // 4 MB
  const size_t SZ_WQ = (size_t)768*256*2;
  const size_t SZ_WP = (size_t)256*256*2;
  if(ws_size < SZ_XT + SZ_VT + SZ_WQ + SZ_WP) return;   // need ~8.9 MB scratch

  char* ws = (char*)d_ws;
  __hip_bfloat16* xt  = (__hip_bfloat16*)ws;
  __hip_bfloat16* vt  = (__hip_bfloat16*)(ws + SZ_XT);
  __hip_bfloat16* wqb = (__hip_bfloat16*)(ws + SZ_XT + SZ_VT);
  __hip_bfloat16* wpb = (__hip_bfloat16*)(ws + SZ_XT + SZ_VT + SZ_WQ);
  // q,k live in d_out (8 MB): dead before proj overwrites d_out with the result.
  __hip_bfloat16* qb  = (__hip_bfloat16*)d_out;
  __hip_bfloat16* kb  = qb + (size_t)2*1024*1024;
  __hip_bfloat16* ost = xt;                   // xt dead after k_qkv

  k_prep<<<dim3(64,4,2), 256, 0, stream>>>(x, wqkv, wproj, xt, wqb, wpb);
  k_qkv<<<384, 256, 0, stream>>>(wqb, xt, qb, kb, vt);
  k_attn<<<1024, 256, 0, stream>>>(qb, kb, vt, ost);
  k_proj<<<512, 256, 0, stream>>>(wpb, ost, out);
}